// Round 9
// baseline (178.260 us; speedup 1.0000x reference)
//
#include <hip/hip_runtime.h>
#include <cstdint>
#include <cstddef>

// Problem constants
#define NUM_CODES 1024
#define DIM       256
#define NROWS     65536          // BATCH(8192) * NODE(8)
#define BM        64             // rows per tile
#define LDS_STRIDE 272           // 256 fp8 bytes + 16 pad (16B-aligned rows)
#define T_TILES   4              // tiles per persistent block
#define GRID_MAIN (NROWS / BM / T_TILES)   // 256 blocks = 1 per CU
#define OUT0_ELEMS 16777216      // 8192*8*256

typedef float v4f  __attribute__((ext_vector_type(4)));
typedef int   v4i  __attribute__((ext_vector_type(4)));
typedef int   v8i  __attribute__((ext_vector_type(8)));

// v_cvt_pk_fp8_f32: word-select (4th arg) must be a compile-time constant.
__device__ inline unsigned cvt_pk_fp8_lo(float lo, float hi) {
  return (unsigned)__builtin_amdgcn_cvt_pk_fp8_f32(lo, hi, 0, false);
}
__device__ inline unsigned cvt_pk_fp8_hi(float lo, float hi, unsigned old) {
  return (unsigned)__builtin_amdgcn_cvt_pk_fp8_f32(lo, hi, (int)old, true);
}

// load 32 bytes (16B-aligned) as the v8i MFMA operand
__device__ inline v8i ld32(const void* p) {
  v4i lo = *(const v4i*)p;
  v4i hi = *(const v4i*)((const char*)p + 16);
  return (v8i){lo.x, lo.y, lo.z, lo.w, hi.x, hi.y, hi.z, hi.w};
}

// One block per code k (1024 blocks, 256 threads = one per d).
// B stored as e4m3 of (512*e): raw e in (-1e-3,1e-3) is DENORMAL in e4m3 --
// scaling by 512 puts it in the normal range.
// c0[k] = 256 - 256*||e||^2 : MFMA C-init, so after the K-loop
// acc = 256 + 512*(dot - ||e||^2/2) in [82, 430] > 0 (Cauchy-Schwarz worst case)
// => u32 compare == f32 compare for the packed argmax key.
// eprep in the K=128 MX fragment layout for mfma_scale_f32_16x16x128_f8f6f4:
// lane l holds B[k=(l>>4)*32+j][col=l&15], j=0..31; tile = (c16, kk2) of 2048B.
__global__ __launch_bounds__(256) void vq_prep(const float* __restrict__ emb,
                                               unsigned char* __restrict__ eprep,
                                               float* __restrict__ c0,
                                               float* __restrict__ loss_slot) {
  const int k = blockIdx.x;
  const int d = threadIdx.x;
  float v = emb[k * DIM + d];

  float sq = v * v;
  #pragma unroll
  for (int off = 32; off; off >>= 1) sq += __shfl_down(sq, off);
  __shared__ float red[4];
  const int lane = threadIdx.x & 63, wv = threadIdx.x >> 6;
  if (lane == 0) red[wv] = sq;
  __syncthreads();
  if (threadIdx.x == 0) c0[k] = 256.0f - 256.0f * (red[0] + red[1] + red[2] + red[3]);
  if (blockIdx.x == 0 && threadIdx.x == 0) *loss_slot = 0.0f;

  const int c16 = k >> 4;
  const int kk2 = d >> 7;          // which K=128 slice (0..1)
  const int q   = (d >> 5) & 3;    // 32-block within the slice
  const int j   = d & 31;
  const int l   = q * 16 + (k & 15);
  const unsigned b8 = cvt_pk_fp8_lo(512.0f * v, 512.0f * v) & 0xFFu;
  eprep[(((c16 * 2 + kk2) * 64) + l) * 32 + j] = (unsigned char)b8;
}

// Persistent pipelined: 256 blocks (1/CU) x 512 threads (8 waves), T=4 tiles.
// R8 diagnosis: 4 generations/CU ran SERIALLY (occupancy ~1.2 blocks/CU; wall
// ~= 4 x [stage 2.6 + compute 4 + epilogue 2.6]us). Fix: pipeline inside the
// block -- issue tile t+1's global loads (32 VGPRs) before compute(t), so the
// HBM read hides under compute+epilogue; convert+LDS-write into the other
// buffer after the epilogue. This is R1's structure retried at the R8 lean
// register footprint (acc[4]=16, est ~115 regs vs R1's 160+spill).
// R1/R2 law: (512,2) only. R3: plain stores. R6: no hand-pinning of loops.
__global__ __launch_bounds__(512, 2) void vq_main(const float* __restrict__ lat,
                                                  const float* __restrict__ emb,
                                                  const unsigned char* __restrict__ eprep,
                                                  const float* __restrict__ c0arr,
                                                  float* __restrict__ out,
                                                  float* __restrict__ loss_slot) {
  __shared__ __align__(16) unsigned char xlds[2][BM * LDS_STRIDE];  // ~34.8 KB
  __shared__ unsigned smax[2][BM];
  __shared__ float lred[8];

  const int tid = threadIdx.x;
  const int lane = tid & 63;
  const int cg = tid >> 6;           // wave 0..7 = code-group (16 codes per ct)
  const int lane15 = lane & 15;
  const int q4 = lane >> 4;          // 32-block index within K=128
  const size_t tbase = (size_t)blockIdx.x * T_TILES;

  // per-ct column constants, persistent across all tiles
  float c0v[8];
  #pragma unroll
  for (int ct = 0; ct < 8; ++ct)
    c0v[ct] = c0arr[ct * 128 + cg * 16 + lane15];

  float x2 = 0.0f;      // sum ||x||^2 (all threads)
  float ssum = 0.0f;    // sum of winning scaled scores (wave 0 only)
  v4f sreg[8];

  // ---- prologue: load + convert tile 0 into buf 0 ----
  {
    const v4f* lp = (const v4f*)(lat + tbase * (BM * DIM));
    #pragma unroll
    for (int i = 0; i < 8; ++i) sreg[i] = lp[i * 512 + tid];
  }
  if (tid < BM) { smax[0][tid] = 0u; smax[1][tid] = 0u; }
  #pragma unroll
  for (int i = 0; i < 8; ++i) {
    const int g = i * 512 + tid, row = g >> 6, c4 = g & 63;
    const v4f v = sreg[i];
    x2 = fmaf(v.x, v.x, x2); x2 = fmaf(v.y, v.y, x2);
    x2 = fmaf(v.z, v.z, x2); x2 = fmaf(v.w, v.w, x2);
    unsigned w = cvt_pk_fp8_lo(v.x, v.y);
    w = cvt_pk_fp8_hi(v.z, v.w, w);
    *(unsigned*)(&xlds[0][row * LDS_STRIDE + c4 * 4]) = w;
  }
  __syncthreads();

  for (int t = 0; t < T_TILES; ++t) {
    const int buf = t & 1;

    // issue next tile's global loads NOW; consumed after the epilogue
    if (t + 1 < T_TILES) {
      const v4f* lp = (const v4f*)(lat + (tbase + t + 1) * (BM * DIM));
      #pragma unroll
      for (int i = 0; i < 8; ++i) sreg[i] = lp[i * 512 + tid];
    }
    // reset the buffer read by epilogue(t-1); two barriers separate this
    // write from the next atomicMax use at compute(t+1) -> race-free.
    if (t > 0 && tid < BM) smax[buf ^ 1][tid] = 0u;

    // ---- compute tile t from xlds[buf] ----
    unsigned kmax[16];
    #pragma unroll
    for (int s = 0; s < 16; ++s) kmax[s] = 0u;

    for (int ct = 0; ct < 8; ++ct) {           // 8 code tiles of 128 (16/wave)
      const int cb = ct * 128 + cg * 16;
      const int c16b = cb >> 4;

      v4f acc[4];
      #pragma unroll
      for (int mf = 0; mf < 4; ++mf)
        acc[mf] = (v4f){c0v[ct], c0v[ct], c0v[ct], c0v[ct]};

      v8i b[2];
      #pragma unroll
      for (int kk2 = 0; kk2 < 2; ++kk2)
        b[kk2] = ld32(eprep + (((size_t)(c16b * 2 + kk2) * 64) + lane) * 32);

      #pragma unroll
      for (int kk2 = 0; kk2 < 2; ++kk2)
        #pragma unroll
        for (int mf = 0; mf < 4; ++mf) {
          const v8i a = ld32(&xlds[buf][(mf * 16 + lane15) * LDS_STRIDE + kk2 * 128 + q4 * 32]);
          acc[mf] = __builtin_amdgcn_mfma_scale_f32_16x16x128_f8f6f4(
              a, b[kk2], acc[mf], 0, 0,               // cbsz=0 (e4m3), blgp=0 (e4m3)
              0, 0x7F7F7F7F, 0, 0x7F7F7F7F);          // scales = 1.0 (e8m0 127)
        }

      const unsigned cc = (unsigned)(1023 - (cb + lane15));
      #pragma unroll
      for (int mf = 0; mf < 4; ++mf)
        #pragma unroll
        for (int i = 0; i < 4; ++i) {
          const unsigned key =
              (__builtin_bit_cast(unsigned, acc[mf][i]) & 0xFFFFFC00u) | cc;
          const int s = mf * 4 + i;
          kmax[s] = key > kmax[s] ? key : kmax[s];
        }
    }

    // reduce across the 16 lanes sharing a quad (single u32 max)
    #pragma unroll
    for (int s = 0; s < 16; ++s) {
      #pragma unroll
      for (int mask = 1; mask <= 8; mask <<= 1) {
        const unsigned o = __shfl_xor(kmax[s], mask);
        kmax[s] = o > kmax[s] ? o : kmax[s];
      }
    }
    if (lane15 == 0) {
      #pragma unroll
      for (int mf = 0; mf < 4; ++mf)
        #pragma unroll
        for (int i = 0; i < 4; ++i)
          atomicMax(&smax[buf][mf * 16 + q4 * 4 + i], kmax[mf * 4 + i]);
    }
    __syncthreads();                           // B1: smax[buf] final

    // ---- epilogue: gather + store. wave cg owns rows cg*8..cg*8+7 ----
    float* outg = out + (tbase + t) * (BM * DIM);
    #pragma unroll
    for (int j = 0; j < 8; ++j) {
      const int r = cg * 8 + j;
      const int code = (int)((~smax[buf][r]) & 1023u);
      const v4f ev = *(const v4f*)(emb + code * DIM + lane * 4);
      *(v4f*)(outg + (size_t)r * DIM + lane * 4) = ev;
    }
    if (cg == 0)   // accumulate winning scores for the loss
      ssum += __builtin_bit_cast(float, smax[buf][lane] & 0xFFFFFC00u) - 256.0f;

    // ---- convert prefetched tile into the other buffer ----
    if (t + 1 < T_TILES) {
      #pragma unroll
      for (int i = 0; i < 8; ++i) {
        const int g = i * 512 + tid, row = g >> 6, c4 = g & 63;
        const v4f v = sreg[i];
        x2 = fmaf(v.x, v.x, x2); x2 = fmaf(v.y, v.y, x2);
        x2 = fmaf(v.z, v.z, x2); x2 = fmaf(v.w, v.w, x2);
        unsigned w = cvt_pk_fp8_lo(v.x, v.y);
        w = cvt_pk_fp8_hi(v.z, v.w, w);
        *(unsigned*)(&xlds[buf ^ 1][row * LDS_STRIDE + c4 * 4]) = w;
      }
    }
    __syncthreads();                           // B2: next buffer ready
  }

  // ---- loss: dist_row = ||x||^2 - 2*(acc_win-256)/512; one atomic/block ----
  #pragma unroll
  for (int off = 32; off; off >>= 1) x2 += __shfl_down(x2, off);
  if (lane == 0) lred[cg] = x2;
  if (cg == 0) {
    #pragma unroll
    for (int off = 32; off; off >>= 1) ssum += __shfl_down(ssum, off);
  }
  __syncthreads();
  if (tid == 0) {
    float xs = 0.0f;
    #pragma unroll
    for (int c = 0; c < 8; ++c) xs += lred[c];
    atomicAdd(loss_slot, (xs - ssum * (2.0f / 512.0f)) * (1.25f / 16777216.0f));
  }
}

extern "C" void kernel_launch(void* const* d_in, const int* in_sizes, int n_in,
                              void* d_out, int out_size, void* d_ws, size_t ws_size,
                              hipStream_t stream) {
  const float* lat = (const float*)d_in[0];   // [8192, 2048] fp32
  const float* emb = (const float*)d_in[1];   // [1024, 256] fp32
  float* out = (float*)d_out;                 // [16777216] quantized_st + [1] vq_loss
  unsigned char* eprep = (unsigned char*)d_ws;                      // 256 KiB
  float* c0 = (float*)((char*)d_ws + NUM_CODES * DIM);
  float* loss_slot = out + (size_t)OUT0_ELEMS;

  vq_prep<<<NUM_CODES, 256, 0, stream>>>(emb, eprep, c0, loss_slot);
  vq_main<<<GRID_MAIN, 512, 0, stream>>>(lat, emb, eprep, c0, out, loss_slot);
}

// Round 10
// 140.305 us; speedup vs baseline: 1.2705x; 1.2705x over previous
//
#include <hip/hip_runtime.h>
#include <cstdint>
#include <cstddef>

// Problem constants
#define NUM_CODES 1024
#define DIM       256
#define NROWS     65536          // BATCH(8192) * NODE(8)
#define BM        64             // rows per tile
#define LSTR      272            // fp8 tile stride: 256 + 16 pad (2-way banks)
#define T_TILES   4              // tiles per persistent block
#define GRID_MAIN (NROWS / BM / T_TILES)   // 256 blocks = 1 per CU
#define OUT0_ELEMS 16777216      // 8192*8*256

typedef float v4f  __attribute__((ext_vector_type(4)));
typedef int   v4i  __attribute__((ext_vector_type(4)));
typedef int   v8i  __attribute__((ext_vector_type(8)));

// v_cvt_pk_fp8_f32: word-select (4th arg) must be a compile-time constant.
__device__ inline unsigned cvt_pk_fp8_lo(float lo, float hi) {
  return (unsigned)__builtin_amdgcn_cvt_pk_fp8_f32(lo, hi, 0, false);
}
__device__ inline unsigned cvt_pk_fp8_hi(float lo, float hi, unsigned old) {
  return (unsigned)__builtin_amdgcn_cvt_pk_fp8_f32(lo, hi, (int)old, true);
}

// async global->LDS DMA, 16B per lane. LDS dest is WAVE-UNIFORM base + lane*16;
// global src is per-lane. Zero register cost (the R1/R9 spill killer).
__device__ inline void gld16(const void* g, void* l) {
  __builtin_amdgcn_global_load_lds(
      (const __attribute__((address_space(1))) unsigned int*)g,
      (__attribute__((address_space(3))) unsigned int*)l, 16, 0, 0);
}

#define WAITV(N) asm volatile("s_waitcnt vmcnt(" #N ")" ::: "memory")
#define WAITL()  asm volatile("s_waitcnt lgkmcnt(0)" ::: "memory")
#define BAR()    __builtin_amdgcn_s_barrier()

// load 32 bytes (16B-aligned) as the v8i MFMA operand
__device__ inline v8i ld32(const void* p) {
  v4i lo = *(const v4i*)p;
  v4i hi = *(const v4i*)((const char*)p + 16);
  return (v8i){lo.x, lo.y, lo.z, lo.w, hi.x, hi.y, hi.z, hi.w};
}

// One block per code k (1024 blocks, 256 threads = one per d).
// B stored as e4m3 of (512*e) -- raw e is denormal in e4m3, x512 normalizes.
// c0[k] = 256 - 256*||e||^2 : MFMA C-init => acc = 256 + 512*(dot - ||e||^2/2)
// in [82,430] > 0 (Cauchy-Schwarz) => u32 compare == f32 compare (packed argmax).
// eprep in the K=128 MX fragment layout (R8-verified).
__global__ __launch_bounds__(256) void vq_prep(const float* __restrict__ emb,
                                               unsigned char* __restrict__ eprep,
                                               float* __restrict__ c0,
                                               float* __restrict__ loss_slot) {
  const int k = blockIdx.x;
  const int d = threadIdx.x;
  float v = emb[k * DIM + d];

  float sq = v * v;
  #pragma unroll
  for (int off = 32; off; off >>= 1) sq += __shfl_down(sq, off);
  __shared__ float red[4];
  const int lane = threadIdx.x & 63, wv = threadIdx.x >> 6;
  if (lane == 0) red[wv] = sq;
  __syncthreads();
  if (threadIdx.x == 0) c0[k] = 256.0f - 256.0f * (red[0] + red[1] + red[2] + red[3]);
  if (blockIdx.x == 0 && threadIdx.x == 0) *loss_slot = 0.0f;

  const int c16 = k >> 4;
  const int kk2 = d >> 7;          // K=128 slice (0..1)
  const int q   = (d >> 5) & 3;    // 32-block within the slice
  const int j   = d & 31;
  const int l   = q * 16 + (k & 15);
  const unsigned b8 = cvt_pk_fp8_lo(512.0f * v, 512.0f * v) & 0xFFu;
  eprep[(((c16 * 2 + kk2) * 64) + l) * 32 + j] = (unsigned char)b8;
}

// Persistent pipelined, 256 blocks (1/CU) x 512 threads, T=4 tiles.
// R1/R9 law (3 strikes): register-staged prefetch ALWAYS spills here -> staging
// must be zero-register: global_load_lds DMA of RAW fp32 into a 2x64KB LDS
// arena; convert LDS->LDS into the padded fp8 tile (R8's VALU, cheaper source).
// Raw s_barrier + counted vmcnt (m139: raw barrier does NOT drain vmcnt) keep
// tile t+1's DMA in flight under convert+compute+epilogue of tile t.
// vmcnt(16) at loop end: outstanding <= 8 DMA(oldest)+8 gathers+8 stores; <=16
// left => the 8 oldest (DMAs) retired. R3: plain stores. R6: no loop pinning.
__global__ __launch_bounds__(512) void vq_main(const float* __restrict__ lat,
                                               const float* __restrict__ emb,
                                               const unsigned char* __restrict__ eprep,
                                               const float* __restrict__ c0arr,
                                               float* __restrict__ out,
                                               float* __restrict__ loss_slot) {
  __shared__ __align__(16) float fbuf[2][BM * DIM];        // 2 x 64 KB raw fp32
  __shared__ __align__(16) unsigned char xq[BM * LSTR];    // 17 KB fp8 tile
  __shared__ unsigned smax[BM];
  __shared__ float lred[8];

  const int tid = threadIdx.x;
  const int lane = tid & 63;
  const int cg = tid >> 6;           // wave 0..7 = code-group (16 codes per ct)
  const int lane15 = lane & 15;
  const int q4 = lane >> 4;          // 32-block index within K=128
  const size_t tbase = (size_t)blockIdx.x * T_TILES;

  // per-ct column constants, persistent across tiles
  float c0v[8];
  #pragma unroll
  for (int ct = 0; ct < 8; ++ct)
    c0v[ct] = c0arr[ct * 128 + cg * 16 + lane15];

  float x2 = 0.0f;      // sum ||x||^2 (all threads, via convert pass)
  float ssum = 0.0f;    // sum of winning scaled scores (wave 0)

  // ---- prologue: DMA tile 0 into fbuf[0] ----
  {
    const float* gs = lat + tbase * (BM * DIM);
    #pragma unroll
    for (int i = 0; i < 8; ++i) {
      const int base = i * 512 + cg * 64;          // float4 index, wave-uniform
      gld16(gs + (size_t)(base + lane) * 4, &fbuf[0][base * 4]);
    }
  }
  if (tid < BM) smax[tid] = 0u;
  WAITV(0); WAITL(); BAR();

  for (int t = 0; t < T_TILES; ++t) {
    const int bf = t & 1;

    // issue next tile's DMA NOW (zero registers held)
    if (t + 1 < T_TILES) {
      const float* gs = lat + (tbase + t + 1) * (BM * DIM);
      #pragma unroll
      for (int i = 0; i < 8; ++i) {
        const int base = i * 512 + cg * 64;
        gld16(gs + (size_t)(base + lane) * 4, &fbuf[bf ^ 1][base * 4]);
      }
    }

    // ---- convert fbuf[bf] (fp32, ready) -> xq (fp8, padded); accumulate x2 ----
    #pragma unroll
    for (int i = 0; i < 8; ++i) {
      const int g = i * 512 + tid, row = g >> 6, c4 = g & 63;
      const v4f v = *(const v4f*)(&fbuf[bf][g * 4]);
      x2 = fmaf(v.x, v.x, x2); x2 = fmaf(v.y, v.y, x2);
      x2 = fmaf(v.z, v.z, x2); x2 = fmaf(v.w, v.w, x2);
      unsigned w = cvt_pk_fp8_lo(v.x, v.y);
      w = cvt_pk_fp8_hi(v.z, v.w, w);
      *(unsigned*)(&xq[row * LSTR + c4 * 4]) = w;
    }
    WAITL(); BAR();                              // xq + smax reset visible

    // ---- compute tile t (R8's MX core, unchanged) ----
    unsigned kmax[16];
    #pragma unroll
    for (int s = 0; s < 16; ++s) kmax[s] = 0u;

    for (int ct = 0; ct < 8; ++ct) {
      const int cb = ct * 128 + cg * 16;
      const int c16b = cb >> 4;

      v4f acc[4];
      #pragma unroll
      for (int mf = 0; mf < 4; ++mf)
        acc[mf] = (v4f){c0v[ct], c0v[ct], c0v[ct], c0v[ct]};

      v8i b[2];
      #pragma unroll
      for (int kk2 = 0; kk2 < 2; ++kk2)
        b[kk2] = ld32(eprep + (((size_t)(c16b * 2 + kk2) * 64) + lane) * 32);

      #pragma unroll
      for (int kk2 = 0; kk2 < 2; ++kk2)
        #pragma unroll
        for (int mf = 0; mf < 4; ++mf) {
          const v8i a = ld32(&xq[(mf * 16 + lane15) * LSTR + kk2 * 128 + q4 * 32]);
          acc[mf] = __builtin_amdgcn_mfma_scale_f32_16x16x128_f8f6f4(
              a, b[kk2], acc[mf], 0, 0,           // cbsz=0 (e4m3), blgp=0 (e4m3)
              0, 0x7F7F7F7F, 0, 0x7F7F7F7F);      // scales = 1.0 (e8m0 127)
        }

      const unsigned cc = (unsigned)(1023 - (cb + lane15));
      #pragma unroll
      for (int mf = 0; mf < 4; ++mf)
        #pragma unroll
        for (int i = 0; i < 4; ++i) {
          const unsigned key =
              (__builtin_bit_cast(unsigned, acc[mf][i]) & 0xFFFFFC00u) | cc;
          const int s = mf * 4 + i;
          kmax[s] = key > kmax[s] ? key : kmax[s];
        }
    }

    #pragma unroll
    for (int s = 0; s < 16; ++s) {
      #pragma unroll
      for (int mask = 1; mask <= 8; mask <<= 1) {
        const unsigned o = __shfl_xor(kmax[s], mask);
        kmax[s] = o > kmax[s] ? o : kmax[s];
      }
    }
    if (lane15 == 0) {
      #pragma unroll
      for (int mf = 0; mf < 4; ++mf)
        #pragma unroll
        for (int i = 0; i < 4; ++i)
          atomicMax(&smax[mf * 16 + q4 * 4 + i], kmax[mf * 4 + i]);
    }
    WAITL(); BAR();                              // smax final; all xq reads done

    // ---- epilogue: gather + store; wave cg owns rows cg*8..cg*8+7 ----
    float* outg = out + (tbase + t) * (BM * DIM);
    #pragma unroll
    for (int j = 0; j < 8; ++j) {
      const int r = cg * 8 + j;
      const int code = (int)((~smax[r]) & 1023u);
      const v4f ev = *(const v4f*)(emb + code * DIM + lane * 4);
      *(v4f*)(outg + (size_t)r * DIM + lane * 4) = ev;
    }
    if (cg == 0)
      ssum += __builtin_bit_cast(float, smax[lane] & 0xFFFFFC00u) - 256.0f;

    if (t + 1 < T_TILES) {
      // DMA(t+1) done when <=16 vmem remain (8 gathers + 8 stores are younger).
      WAITV(16); BAR();
      if (tid < BM) smax[tid] = 0u;              // epilogue done on all waves
    }
  }

  // ---- loss: dist_row = ||x||^2 - 2*(acc_win-256)/512; one atomic/block ----
  #pragma unroll
  for (int off = 32; off; off >>= 1) x2 += __shfl_down(x2, off);
  if (lane == 0) lred[cg] = x2;
  if (cg == 0) {
    #pragma unroll
    for (int off = 32; off; off >>= 1) ssum += __shfl_down(ssum, off);
  }
  __syncthreads();
  if (tid == 0) {
    float xs = 0.0f;
    #pragma unroll
    for (int c = 0; c < 8; ++c) xs += lred[c];
    atomicAdd(loss_slot, (xs - ssum * (2.0f / 512.0f)) * (1.25f / 16777216.0f));
  }
}

extern "C" void kernel_launch(void* const* d_in, const int* in_sizes, int n_in,
                              void* d_out, int out_size, void* d_ws, size_t ws_size,
                              hipStream_t stream) {
  const float* lat = (const float*)d_in[0];   // [8192, 2048] fp32
  const float* emb = (const float*)d_in[1];   // [1024, 256] fp32
  float* out = (float*)d_out;                 // [16777216] quantized_st + [1] vq_loss
  unsigned char* eprep = (unsigned char*)d_ws;                      // 256 KiB
  float* c0 = (float*)((char*)d_ws + NUM_CODES * DIM);
  float* loss_slot = out + (size_t)OUT0_ELEMS;

  vq_prep<<<NUM_CODES, 256, 0, stream>>>(emb, eprep, c0, loss_slot);
  vq_main<<<GRID_MAIN, 512, 0, stream>>>(lat, emb, eprep, c0, out, loss_slot);
}